// Round 7
// baseline (159.405 us; speedup 1.0000x reference)
//
#include <hip/hip_runtime.h>
#include <hip/hip_bf16.h>

// ContrastiveLoss: z (8192x1024 fp32) -> scalar
//   zn = z / max(||z||,eps); S = zn@zn^T; diag=MASK; /T; nll = -S[i,i^4096] + lse(S[i,:]); mean
// R14: MX-scaled fp8 MFMA retry at LOW register pressure. R8 proved the MX
// path's NUMERICS (mfma_scale_f32_16x16x128_f8f6f4, unit e8m0 scales, absmax
// 0.0) but spilled: acc[4][8]=128 regs + v8i32 tuples filled the unified file.
// R13's cost fit showed stage cost = ds_read instrs + MFMA serialized, with
// the A-side duplicated per N-split. Fix both:
//   - units = 128 rows x 256 cols; 8 waves in 2x4; wave-tile 64x64 ->
//     acc[4][4] = 64 regs; A-frags 4 x v8i32 = 32; B streamed. ~140 regs.
//   - per CU per stage: 128 ds_read_b128 + 128 MX MFMA (~2640 cyc vs R7 7270).
//   - 64 straddle units cover the 32 diag 256^2 tiles: stage ONLY the B panel
//     and read A fragments from it (A rows are a 128-row subrange; swizzle is
//     (row&7)-periodic and offset is 0 or 128 = 0 mod 8, so csw stays valid).
//     rs-only epilogue with diag mask (both orderings of each pair are inside
//     the straddle pair of units -> no cs, no double count, no pos: |i-j|<256).
//   - 992 below units (R13's verified strict-lower decode): rs + cs + pos.
// Spill signature to watch: WRITE_SIZE >> 10MB (R8 hit 624MB, R9 525MB).

#define N 8192
#define D 1024
#define INV_T 14.285714285714286f
#define NBLK 1056  // 64 straddle + 992 below
#define ACC_SCALE (INV_T / 1024.0f)  // undo fp8 x32 scaling on both operands

typedef float f32x4 __attribute__((ext_vector_type(4)));
typedef int i32x4 __attribute__((ext_vector_type(4)));
typedef int i32x8 __attribute__((ext_vector_type(8)));

#define UNIT_SCALE 0x7f7f7f7f  // e8m0 bias 127 -> 2^0 in every byte

__device__ inline void gload16(const void* g, void* l) {
  __builtin_amdgcn_global_load_lds(
      (const __attribute__((address_space(1))) void*)g,
      (__attribute__((address_space(3))) void*)l, 16, 0, 0);
}

// Phase 1: row-normalize z, scale x32, cast fp8 e4m3 -> zn8; zero rowsum.
__global__ __launch_bounds__(256) void k_normalize(const float* __restrict__ z,
                                                   unsigned char* __restrict__ zn8,
                                                   float* __restrict__ rowsum) {
  const int gt = blockIdx.x * 256 + threadIdx.x;
  if (gt < N) rowsum[gt] = 0.0f;
  const int row = gt >> 6;
  const int l = threadIdx.x & 63;
  const float4* zr = (const float4*)(z + (size_t)row * D);
  float4 v[4];
  float ss = 0.f;
#pragma unroll
  for (int j = 0; j < 4; ++j) {
    v[j] = zr[l + 64 * j];  // coalesced: lane-consecutive 16B
    ss += v[j].x * v[j].x + v[j].y * v[j].y + v[j].z * v[j].z + v[j].w * v[j].w;
  }
#pragma unroll
  for (int off = 32; off > 0; off >>= 1) ss += __shfl_xor(ss, off, 64);
  const float sc = 32.0f / fmaxf(sqrtf(ss), 1e-8f);  // e4m3 range; undone by ACC_SCALE
  int* orow = (int*)(zn8 + (size_t)row * D);
#pragma unroll
  for (int j = 0; j < 4; ++j) {
    int p = __builtin_amdgcn_cvt_pk_fp8_f32(v[j].x * sc, v[j].y * sc, 0, false);
    p = __builtin_amdgcn_cvt_pk_fp8_f32(v[j].z * sc, v[j].w * sc, p, true);
    orow[l + 64 * j] = p;  // coalesced 4B stores, same element order as loads
  }
}

// Phase 2: 128x256 units. Blocks 0..63 = straddle (diag region, B-panel only);
// 64..1055 = strictly-below halves. 512 threads (8 waves, 2x4).
// LDS per buffer: A 16KB + B 32KB = 48KB; double-buffered = 96KB dynamic.
__global__ __launch_bounds__(512, 2) void k_tile(const unsigned char* __restrict__ zn8,
                                                 float* __restrict__ rowsum,
                                                 float* __restrict__ pos) {
  extern __shared__ __align__(16) char smem[];  // 98304
  const int tid = threadIdx.x;
  const int w = tid >> 6, l = tid & 63;
  const int wr = w >> 2, wc = w & 3;  // wave-tile 64 rows x 64 cols
  const int m = l & 15, kg = l >> 4;
  const int quad = l >> 4, col = l & 15;

  // staging maps: phys slot s -> row s>>3; phys chunk s&7 holds logical
  // chunk (s&7)^(row&7). A panel: 128 rows x 8 = 1024 slots (j<2);
  // B panel: 256 rows x 8 = 2048 slots (j<4).
  int srow[4], scol[4];
#pragma unroll
  for (int j = 0; j < 4; ++j) {
    int s = j * 512 + tid;
    int r = s >> 3;
    srow[j] = r;
    scol[j] = (s & 7) ^ (r & 7);
  }
  // fragment reads: logical chunks kg, kg+4 (K-permuted; A/B identical)
  const int csw0 = (kg ^ (m & 7)) * 16;
  const int csw1 = ((kg + 4) ^ (m & 7)) * 16;

  const int b = blockIdx.x;
  const bool straddle = (b < 64);
  int row0, col0;
  if (straddle) {
    row0 = b * 128;
    col0 = (b >> 1) * 256;
  } else {
    int p = b - 64;
    const int h = p & 1;
    const int q = p >> 1;
    // strict lower-triangle decode: tr in 1..31, tc < tr (verified in R13)
    int tr = (int)((1.0f + sqrtf(8.0f * (float)q + 1.0f)) * 0.5f);
    if (tr * (tr - 1) / 2 > q) --tr;
    if (tr * (tr + 1) / 2 <= q) ++tr;
    const int tc = q - tr * (tr - 1) / 2;
    row0 = tr * 256 + h * 128;
    col0 = tc * 256;
  }
  const int aoff = row0 - col0;  // straddle: 0 or 128; A rows inside B panel

  f32x4 acc[4][4] = {};

  // prologue: stage kt=0 into buffer 0
  {
    char* ab = smem;
    char* bb = smem + 16384;
    if (!straddle) {
#pragma unroll
      for (int j = 0; j < 2; ++j) {
        const int s = j * 512 + tid;
        gload16((const char*)zn8 + ((size_t)(row0 + srow[j]) * D + scol[j] * 16), ab + s * 16);
      }
    }
#pragma unroll
    for (int j = 0; j < 4; ++j) {
      const int s = j * 512 + tid;
      gload16((const char*)zn8 + ((size_t)(col0 + srow[j]) * D + scol[j] * 16), bb + s * 16);
    }
  }
  __syncthreads();

  for (int kt = 0; kt < 8; ++kt) {
    if (kt < 7) {  // async prefetch kt+1 into other buffer; overlaps MFMA below
      const size_t kb = (size_t)(kt + 1) * 128;
      char* ab = smem + ((kt + 1) & 1) * 49152;
      char* bb = ab + 16384;
      if (!straddle) {
#pragma unroll
        for (int j = 0; j < 2; ++j) {
          const int s = j * 512 + tid;
          gload16((const char*)zn8 + ((size_t)(row0 + srow[j]) * D + kb + scol[j] * 16), ab + s * 16);
        }
      }
#pragma unroll
      for (int j = 0; j < 4; ++j) {
        const int s = j * 512 + tid;
        gload16((const char*)zn8 + ((size_t)(col0 + srow[j]) * D + kb + scol[j] * 16), bb + s * 16);
      }
    }
    const char* ab = smem + (kt & 1) * 49152;
    const char* bb = ab + 16384;
    // A fragments: from A panel, or from inside the B panel for straddle
    // (aoff = 0 or 128; (row&7) pattern unchanged -> same csw swizzle).
    const char* apan = straddle ? (bb + aoff * 128) : ab;

    i32x8 af[4];
#pragma unroll
    for (int mt = 0; mt < 4; ++mt) {
      const char* rp = apan + (wr * 64 + mt * 16 + m) * 128;
      const i32x4 lo = *(const i32x4*)(rp + csw0);
      const i32x4 hi = *(const i32x4*)(rp + csw1);
      af[mt] = __builtin_shufflevector(lo, hi, 0, 1, 2, 3, 4, 5, 6, 7);
    }
#pragma unroll
    for (int nt = 0; nt < 4; ++nt) {
      const char* rp = bb + (wc * 64 + nt * 16 + m) * 128;
      const i32x4 lo = *(const i32x4*)(rp + csw0);
      const i32x4 hi = *(const i32x4*)(rp + csw1);
      const i32x8 bf = __builtin_shufflevector(lo, hi, 0, 1, 2, 3, 4, 5, 6, 7);
#pragma unroll
      for (int mt = 0; mt < 4; ++mt) {
        acc[mt][nt] = __builtin_amdgcn_mfma_scale_f32_16x16x128_f8f6f4(
            af[mt], bf, acc[mt][nt], 0, 0,  // cbsz=0 (fp8 e4m3), blgp=0
            0, UNIT_SCALE, 0, UNIT_SCALE);  // unit block scales: exact fp8 GEMM
      }
    }
    __syncthreads();  // drains prefetch (vmcnt) + guards buffer reuse
  }

  // Epilogue. C/D layout: col=l&15, row=(l>>4)*4+reg (shape-determined).
  if (straddle) {
    // rs-only; mask diagonal; both orderings of each pair live in the
    // straddle pair of units, so no symmetric cs and no pos (|i-j| < 256).
#pragma unroll
    for (int mt = 0; mt < 4; ++mt) {
      float rs[4] = {0.f, 0.f, 0.f, 0.f};
#pragma unroll
      for (int nt = 0; nt < 4; ++nt) {
        const int gcol = col0 + wc * 64 + nt * 16 + col;
#pragma unroll
        for (int r = 0; r < 4; ++r) {
          const int grow = row0 + wr * 64 + mt * 16 + quad * 4 + r;
          const float t = acc[mt][nt][r] * ACC_SCALE;
          rs[r] += (gcol == grow) ? 0.0f : __expf(t - INV_T);
        }
      }
#pragma unroll
      for (int off = 1; off < 16; off <<= 1) {
#pragma unroll
        for (int r = 0; r < 4; ++r) rs[r] += __shfl_xor(rs[r], off, 64);
      }
      if (col == 0) {
#pragma unroll
        for (int r = 0; r < 4; ++r)
          atomicAdd(&rowsum[row0 + wr * 64 + mt * 16 + quad * 4 + r], rs[r]);
      }
    }
  } else {
    float cs[4] = {0.f, 0.f, 0.f, 0.f};
#pragma unroll
    for (int mt = 0; mt < 4; ++mt) {
      float rs[4] = {0.f, 0.f, 0.f, 0.f};
#pragma unroll
      for (int nt = 0; nt < 4; ++nt) {
        const int gcol = col0 + wc * 64 + nt * 16 + col;
#pragma unroll
        for (int r = 0; r < 4; ++r) {
          const int grow = row0 + wr * 64 + mt * 16 + quad * 4 + r;
          const float t = acc[mt][nt][r] * ACC_SCALE;
          if (gcol == (grow ^ (N / 2))) {  // pos pair
            pos[grow] = t;
            pos[gcol] = t;  // S symmetric
          }
          const float e = __expf(t - INV_T);  // grow != gcol always here
          rs[r] += e;
          cs[nt] += e;
        }
      }
#pragma unroll
      for (int off = 1; off < 16; off <<= 1) {
#pragma unroll
        for (int r = 0; r < 4; ++r) rs[r] += __shfl_xor(rs[r], off, 64);
      }
      if (col == 0) {
#pragma unroll
        for (int r = 0; r < 4; ++r)
          atomicAdd(&rowsum[row0 + wr * 64 + mt * 16 + quad * 4 + r], rs[r]);
      }
    }
#pragma unroll
    for (int nt = 0; nt < 4; ++nt) {
      cs[nt] += __shfl_xor(cs[nt], 16, 64);
      cs[nt] += __shfl_xor(cs[nt], 32, 64);
    }
    if (l < 16) {
#pragma unroll
      for (int nt = 0; nt < 4; ++nt)
        atomicAdd(&rowsum[col0 + wc * 64 + nt * 16 + l], cs[nt]);
    }
  }
}

// Phase 3: single block: out = mean(-pos + C + log(rowsum)).
__global__ __launch_bounds__(1024) void k_final(const float* __restrict__ rowsum,
                                                const float* __restrict__ pos,
                                                float* __restrict__ out) {
  const int t = threadIdx.x;
  float s = 0.f;
  for (int i = t; i < N; i += 1024) s += INV_T + __logf(rowsum[i]) - pos[i];
#pragma unroll
  for (int off = 32; off > 0; off >>= 1) s += __shfl_down(s, off, 64);
  __shared__ float red[16];
  if ((t & 63) == 0) red[t >> 6] = s;
  __syncthreads();
  if (t == 0) {
    float tot = 0.f;
#pragma unroll
    for (int j = 0; j < 16; ++j) tot += red[j];
    out[0] = tot * (1.0f / N);
  }
}

extern "C" void kernel_launch(void* const* d_in, const int* in_sizes, int n_in,
                              void* d_out, int out_size, void* d_ws, size_t ws_size,
                              hipStream_t stream) {
  const float* z = (const float*)d_in[0];
  float* out = (float*)d_out;
  char* ws = (char*)d_ws;
  unsigned char* zn8 = (unsigned char*)ws;                    // 8 MiB fp8
  float* rowsum = (float*)(ws + (size_t)N * D);               // 32 KiB
  float* pos = (float*)(ws + (size_t)N * D + (size_t)N * 4);  // 32 KiB

  static bool attr_set = false;
  if (!attr_set) {  // host-side attribute, idempotent, not a stream op
    hipFuncSetAttribute((const void*)k_tile,
                        hipFuncAttributeMaxDynamicSharedMemorySize, 98304);
    attr_set = true;
  }

  k_normalize<<<N / 4, 256, 0, stream>>>(z, zn8, rowsum);
  k_tile<<<NBLK, 512, 98304, stream>>>(zn8, rowsum, pos);
  k_final<<<1, 1024, 0, stream>>>(rowsum, pos, out);
}

// Round 8
// 158.201 us; speedup vs baseline: 1.0076x; 1.0076x over previous
//
#include <hip/hip_runtime.h>
#include <hip/hip_bf16.h>

// ContrastiveLoss: z (8192x1024 fp32) -> scalar
//   zn = z / max(||z||,eps); S = zn@zn^T; diag=MASK; /T; nll = -S[i,i^4096] + lse(S[i,:]); mean
// R15: R7's proven 256^2 fp8 tile (numerics/swizzle/epilogue verbatim) in an
// m201-style 8-phase schedule to break wave lockstep (R7 stage = LDS 2304 +
// MFMA 4970 cyc SERIALIZED; target = overlap -> max). Per BK=64 K-tile:
//   4 phases x {ds_read (A4+B2 / B2) ; [P0: issue stage kt+2] ; s_barrier ;
//               lgkmcnt(0)+sched_barrier(0) ; setprio(1) ; 16 MFMA ; setprio(0) ;
//               s_barrier}
//   4 LDS buffers (4 x 32KB = 128KB), prefetch distance 2, counted vmcnt(4)
//   ONCE per K-tile at its end (tail 0) - never drains in-flight prefetch.
// R10 failed as the documented anti-pattern (counted vmcnt WITHOUT fine
// interleave, m196); this is the full recipe (T3+T4 gate T5).
// Block order: 496 off-diag first, 32 diag LAST -> 3rd dispatch round (16
// blocks) is cheap diagonal tiles (makespan ~ 2*T_off + T_diag, was 3*T_off).
// Swizzle (R9-verified 64B rows): phys chunk c holds logical c^((row>>1)&3);
// fragment csw = (kg ^ ((m>>1)&3))*16, K-permuted identically for A and B.
// Spill guard: WRITE_SIZE >> 10MB = fail (R8 624MB, R9 525MB).

#define N 8192
#define D 1024
#define INV_T 14.285714285714286f
#define NOFF 496
#define NBLK 528
#define ACC_SCALE (INV_T / 1024.0f)  // undo fp8 x32 scaling on both operands

typedef float f32x4 __attribute__((ext_vector_type(4)));
typedef long lx2 __attribute__((ext_vector_type(2)));

#define WAITV(n) asm volatile("s_waitcnt vmcnt(" #n ")" ::: "memory")
#define LGKM0                                      \
  do {                                             \
    asm volatile("s_waitcnt lgkmcnt(0)" ::: "memory"); \
    __builtin_amdgcn_sched_barrier(0);             \
  } while (0)

__device__ inline void gload16(const void* g, void* l) {
  __builtin_amdgcn_global_load_lds(
      (const __attribute__((address_space(1))) void*)g,
      (__attribute__((address_space(3))) void*)l, 16, 0, 0);
}

// Phase 1: row-normalize z, scale x32, cast fp8 e4m3 -> zn8; zero rowsum.
__global__ __launch_bounds__(256) void k_normalize(const float* __restrict__ z,
                                                   unsigned char* __restrict__ zn8,
                                                   float* __restrict__ rowsum) {
  const int gt = blockIdx.x * 256 + threadIdx.x;
  if (gt < N) rowsum[gt] = 0.0f;
  const int row = gt >> 6;
  const int l = threadIdx.x & 63;
  const float4* zr = (const float4*)(z + (size_t)row * D);
  float4 v[4];
  float ss = 0.f;
#pragma unroll
  for (int j = 0; j < 4; ++j) {
    v[j] = zr[l + 64 * j];  // coalesced: lane-consecutive 16B
    ss += v[j].x * v[j].x + v[j].y * v[j].y + v[j].z * v[j].z + v[j].w * v[j].w;
  }
#pragma unroll
  for (int off = 32; off > 0; off >>= 1) ss += __shfl_xor(ss, off, 64);
  const float sc = 32.0f / fmaxf(sqrtf(ss), 1e-8f);  // e4m3 range; undone by ACC_SCALE
  int* orow = (int*)(zn8 + (size_t)row * D);
#pragma unroll
  for (int j = 0; j < 4; ++j) {
    int p = __builtin_amdgcn_cvt_pk_fp8_f32(v[j].x * sc, v[j].y * sc, 0, false);
    p = __builtin_amdgcn_cvt_pk_fp8_f32(v[j].z * sc, v[j].w * sc, p, true);
    orow[j * 64 + l] = p;  // coalesced 4B stores, same element order as loads
  }
}

// Phase 2: 256x256 tiles, 512 threads (8 waves, 4x2), 8-phase pipelined.
// BK=64 K-tiles; 4 buffers x (A 16KB + B 16KB) = 128KB dynamic LDS.
__global__ __launch_bounds__(512, 2) void k_tile(const unsigned char* __restrict__ zn8,
                                                 float* __restrict__ rowsum,
                                                 float* __restrict__ pos) {
  extern __shared__ __align__(16) char smem[];  // 131072
  const int tid = threadIdx.x;
  const int w = tid >> 6, l = tid & 63;
  const int wr = w >> 1, wc = w & 1;  // wave tile: 64 rows x 128 cols
  const int m = l & 15, kg = l >> 4;
  const int quad = l >> 4, col = l & 15;

  // block decode: 0..495 strict-lower (tr 1..31, tc<tr); 496..527 diag (LAST)
  const int b = blockIdx.x;
  int tr, tc;
  if (b < NOFF) {
    const int q = b;
    tr = (int)((1.0f + sqrtf(8.0f * (float)q + 1.0f)) * 0.5f);
    if (tr * (tr - 1) / 2 > q) --tr;
    if (tr * (tr + 1) / 2 <= q) ++tr;
    tc = q - tr * (tr - 1) / 2;
  } else {
    tr = tc = b - NOFF;
  }
  const bool diag = (tr == tc);
  const int rowA0 = tr * 256, colB0 = tc * 256;

  // staging: per matrix per K-tile 1024 slots x 16B (256 rows x 4 chunks).
  // phys slot s -> row s>>2; phys chunk s&3 holds logical chunk (s&3)^((r>>1)&3).
  int srow[2], scol[2];
#pragma unroll
  for (int j = 0; j < 2; ++j) {
    const int s = j * 512 + tid;
    const int r = s >> 2;
    srow[j] = r;
    scol[j] = (s & 3) ^ ((r >> 1) & 3);
  }
  // fragment read: logical chunk kg (16B = both K32 halves, K-permuted; A/B identical)
  const int csw = (kg ^ ((m >> 1) & 3)) * 16;

  f32x4 acc[4][8] = {};

  auto stage = [&](int kt2) {
    const size_t kb = (size_t)kt2 * 64;
    char* ab = smem + (kt2 & 3) * 32768;
#pragma unroll
    for (int j = 0; j < 2; ++j) {
      const int s = j * 512 + tid;
      gload16((const char*)zn8 + ((size_t)(rowA0 + srow[j]) * D + kb + scol[j] * 16), ab + s * 16);
    }
    if (!diag) {
      char* bb = ab + 16384;
#pragma unroll
      for (int j = 0; j < 2; ++j) {
        const int s = j * 512 + tid;
        gload16((const char*)zn8 + ((size_t)(colB0 + srow[j]) * D + kb + scol[j] * 16), bb + s * 16);
      }
    }
  };

  // prologue: buffers 0 and 1 in flight; publish buffer 0
  stage(0);
  stage(1);
  if (!diag) WAITV(4); else WAITV(2);
  __syncthreads();

  for (int kt = 0; kt < 16; ++kt) {
    const char* ab = smem + (kt & 3) * 32768;
    const char* bb = diag ? ab : (ab + 16384);

    // ---- phase 0: A frags + B pair {0,1}; issue stage kt+2 ----
    lx2 a[4];
#pragma unroll
    for (int mt = 0; mt < 4; ++mt)
      a[mt] = *(const lx2*)(ab + (wr * 64 + mt * 16 + m) * 64 + csw);
    lx2 b0 = *(const lx2*)(bb + (wc * 128 + 0 * 16 + m) * 64 + csw);
    lx2 b1 = *(const lx2*)(bb + (wc * 128 + 1 * 16 + m) * 64 + csw);
    if (kt < 14) stage(kt + 2);
    __builtin_amdgcn_s_barrier();
    LGKM0;
    __builtin_amdgcn_s_setprio(1);
#pragma unroll
    for (int mt = 0; mt < 4; ++mt) {
      acc[mt][0] = __builtin_amdgcn_mfma_f32_16x16x32_fp8_fp8(a[mt].x, b0.x, acc[mt][0], 0, 0, 0);
      acc[mt][0] = __builtin_amdgcn_mfma_f32_16x16x32_fp8_fp8(a[mt].y, b0.y, acc[mt][0], 0, 0, 0);
      acc[mt][1] = __builtin_amdgcn_mfma_f32_16x16x32_fp8_fp8(a[mt].x, b1.x, acc[mt][1], 0, 0, 0);
      acc[mt][1] = __builtin_amdgcn_mfma_f32_16x16x32_fp8_fp8(a[mt].y, b1.y, acc[mt][1], 0, 0, 0);
    }
    __builtin_amdgcn_s_setprio(0);
    __builtin_amdgcn_s_barrier();

    // ---- phases 1..3: B pairs {2p,2p+1} ----
#pragma unroll
    for (int ph = 1; ph < 4; ++ph) {
      const int n0 = 2 * ph;
      b0 = *(const lx2*)(bb + (wc * 128 + n0 * 16 + m) * 64 + csw);
      b1 = *(const lx2*)(bb + (wc * 128 + (n0 + 1) * 16 + m) * 64 + csw);
      __builtin_amdgcn_s_barrier();
      LGKM0;
      __builtin_amdgcn_s_setprio(1);
#pragma unroll
      for (int mt = 0; mt < 4; ++mt) {
        acc[mt][n0] = __builtin_amdgcn_mfma_f32_16x16x32_fp8_fp8(a[mt].x, b0.x, acc[mt][n0], 0, 0, 0);
        acc[mt][n0] = __builtin_amdgcn_mfma_f32_16x16x32_fp8_fp8(a[mt].y, b0.y, acc[mt][n0], 0, 0, 0);
        acc[mt][n0 + 1] = __builtin_amdgcn_mfma_f32_16x16x32_fp8_fp8(a[mt].x, b1.x, acc[mt][n0 + 1], 0, 0, 0);
        acc[mt][n0 + 1] = __builtin_amdgcn_mfma_f32_16x16x32_fp8_fp8(a[mt].y, b1.y, acc[mt][n0 + 1], 0, 0, 0);
      }
      __builtin_amdgcn_s_setprio(0);
      if (ph < 3) __builtin_amdgcn_s_barrier();
    }

    // ---- end of K-tile: counted wait publishes buf[kt+1] (never drains deep) ----
    if (kt < 14) {
      if (!diag) WAITV(4); else WAITV(2);
    } else if (kt == 14) {
      WAITV(0);
    }
    __builtin_amdgcn_s_barrier();
  }
  asm volatile("" ::: "memory");

  // Epilogue (R7-verified). C/D layout: col=l&15, row=(l>>4)*4+reg.
  float cs[8] = {0.f, 0.f, 0.f, 0.f, 0.f, 0.f, 0.f, 0.f};
#pragma unroll
  for (int mt = 0; mt < 4; ++mt) {
    float rs[4] = {0.f, 0.f, 0.f, 0.f};
#pragma unroll
    for (int nt = 0; nt < 8; ++nt) {
      const int gcol = colB0 + wc * 128 + nt * 16 + col;
#pragma unroll
      for (int r = 0; r < 4; ++r) {
        const int grow = rowA0 + wr * 64 + mt * 16 + quad * 4 + r;
        const float t = acc[mt][nt][r] * ACC_SCALE;
        if (gcol == (grow ^ (N / 2))) {  // pos pair; never true in diag tiles
          pos[grow] = t;
          pos[gcol] = t;  // S symmetric
        }
        const float e = (gcol == grow) ? 0.0f : __expf(t - INV_T);
        rs[r] += e;
        cs[nt] += e;
      }
    }
#pragma unroll
    for (int off = 1; off < 16; off <<= 1) {
#pragma unroll
      for (int r = 0; r < 4; ++r) rs[r] += __shfl_xor(rs[r], off, 64);
    }
    if (col == 0) {
#pragma unroll
      for (int r = 0; r < 4; ++r)
        atomicAdd(&rowsum[rowA0 + wr * 64 + mt * 16 + quad * 4 + r], rs[r]);
    }
  }
  if (!diag) {  // col sums = row-sums for block tc rows (symmetry)
#pragma unroll
    for (int nt = 0; nt < 8; ++nt) {
      cs[nt] += __shfl_xor(cs[nt], 16, 64);
      cs[nt] += __shfl_xor(cs[nt], 32, 64);
    }
    if (l < 16) {
#pragma unroll
      for (int nt = 0; nt < 8; ++nt)
        atomicAdd(&rowsum[colB0 + wc * 128 + nt * 16 + l], cs[nt]);
    }
  }
}

// Phase 3: single block: out = mean(-pos + C + log(rowsum)).
__global__ __launch_bounds__(1024) void k_final(const float* __restrict__ rowsum,
                                                const float* __restrict__ pos,
                                                float* __restrict__ out) {
  const int t = threadIdx.x;
  float s = 0.f;
  for (int i = t; i < N; i += 1024) s += INV_T + __logf(rowsum[i]) - pos[i];
#pragma unroll
  for (int off = 32; off > 0; off >>= 1) s += __shfl_down(s, off, 64);
  __shared__ float red[16];
  if ((t & 63) == 0) red[t >> 6] = s;
  __syncthreads();
  if (t == 0) {
    float tot = 0.f;
#pragma unroll
    for (int j = 0; j < 16; ++j) tot += red[j];
    out[0] = tot * (1.0f / N);
  }
}

extern "C" void kernel_launch(void* const* d_in, const int* in_sizes, int n_in,
                              void* d_out, int out_size, void* d_ws, size_t ws_size,
                              hipStream_t stream) {
  const float* z = (const float*)d_in[0];
  float* out = (float*)d_out;
  char* ws = (char*)d_ws;
  unsigned char* zn8 = (unsigned char*)ws;                    // 8 MiB fp8
  float* rowsum = (float*)(ws + (size_t)N * D);               // 32 KiB
  float* pos = (float*)(ws + (size_t)N * D + (size_t)N * 4);  // 32 KiB

  static bool attr_set = false;
  if (!attr_set) {  // host-side attribute, idempotent, not a stream op
    hipFuncSetAttribute((const void*)k_tile,
                        hipFuncAttributeMaxDynamicSharedMemorySize, 131072);
    attr_set = true;
  }

  k_normalize<<<N / 4, 256, 0, stream>>>(z, zn8, rowsum);
  k_tile<<<NBLK, 512, 131072, stream>>>(zn8, rowsum, pos);
  k_final<<<1, 1024, 0, stream>>>(rowsum, pos, out);
}